// Round 4
// baseline (246.817 us; speedup 1.0000x reference)
//
#include <hip/hip_runtime.h>

#define NAG 256
#define HID 128
#define ACT 5
#define NH 4
#define DD 144      // concat dim
#define EE 576      // embed dim
#define HDIM 144    // per-head dim
#define CMAX 20     // fast-path neighbor cap

// ===========================================================================
// k_qkv: fully fused per-row-block QKV in the REFERENCE order:
//   C8 = concat(hidden8 @ W_enc + b_enc, action8)            (8 x 144, LDS)
//   T8 = C8 @ Wz + bz                                        (8 x 576, LDS)
//   out_z8[:, cs*192..+192) = T8 @ Wiz + biz                 -> global
// Grid 288 = 32 row-tiles x 3 z x 3 col-thirds. No inter-block deps, no
// precomputed weight products, no bias kernels. All LDS reads of C8/T8 are
// wave-broadcast b128 (conflict-free); W streams are coalesced 256B/wave.
// ===========================================================================
__global__ __launch_bounds__(256) void k_qkv(
    const float* __restrict__ hidden, const float* __restrict__ action,
    const float* __restrict__ W_enc, const float* __restrict__ b_enc,
    const float* __restrict__ Wq, const float* __restrict__ bq,
    const float* __restrict__ Wiq, const float* __restrict__ biq,
    const float* __restrict__ Wk, const float* __restrict__ bk,
    const float* __restrict__ Wik, const float* __restrict__ bik,
    const float* __restrict__ Wv, const float* __restrict__ bv,
    const float* __restrict__ Wiv, const float* __restrict__ biv,
    float* __restrict__ q, float* __restrict__ kb, float* __restrict__ v)
{
    __shared__ float Hs[8 * 132];    // 1056
    __shared__ float We[2048];       // W_enc 128x16
    __shared__ float C8[8 * 148];    // 1184 (row stride 148: float4-aligned)
    __shared__ float T8[8 * 580];    // 4640 (row stride 580: float4-aligned)
    const int p = blockIdx.x, tid = threadIdx.x;
    const int mt = p & 31, zc = p >> 5;         // mt 0..31, zc 0..8
    const int z = zc / 3, cs = zc % 3;
    const float* Wz = (z == 0) ? Wq  : (z == 1) ? Wk  : Wv;
    const float* bz = (z == 0) ? bq  : (z == 1) ? bk  : bv;
    const float* Wi = (z == 0) ? Wiq : (z == 1) ? Wik : Wiv;
    const float* bi = (z == 0) ? biq : (z == 1) ? bik : biv;
    float*     outp = (z == 0) ? q   : (z == 1) ? kb  : v;
    const int row0 = mt * 8;

    // ---- stage A: stage inputs, build C8 ----
    {
        int r = tid >> 5, k4 = tid & 31;
        *((float4*)&Hs[r * 132 + k4 * 4]) =
            *(const float4*)(hidden + (size_t)(row0 + r) * HID + k4 * 4);
        *((float4*)&C8[r * 148 + 16 + k4 * 4]) =
            *(const float4*)(action + (size_t)(row0 + r) * HID + k4 * 4);
        *((float4*)&We[tid * 4])        = *(const float4*)(W_enc + tid * 4);
        *((float4*)&We[1024 + tid * 4]) = *(const float4*)(W_enc + 1024 + tid * 4);
    }
    __syncthreads();
    if (tid < 128) {
        int r = tid >> 4, o = tid & 15;
        float acc = 0.f;
        #pragma unroll 8
        for (int d = 0; d < HID; ++d) acc += Hs[r * 132 + d] * We[d * 16 + o];
        C8[r * 148 + o] = acc + b_enc[o];
    }
    __syncthreads();

    // ---- stage B: T8 = C8 @ Wz + bz (all 576 cols) ----
    // thread owns cols c0=tid, c1=tid+256, c2=tid+512 (tid<64 only)
    {
        const int c0 = tid, c1 = tid + 256, c2 = tid + 512;
        const bool has2 = (tid < 64);
        float a0[8] = {}, a1[8] = {}, a2[8] = {};
        float w0[8], w1[8], w2[8], n0[8], n1[8], n2[8];
        #pragma unroll
        for (int j = 0; j < 8; ++j) {
            w0[j] = Wz[(size_t)j * EE + c0];
            w1[j] = Wz[(size_t)j * EE + c1];
            w2[j] = has2 ? Wz[(size_t)j * EE + c2] : 0.f;
        }
        for (int g = 0; g < 18; ++g) {          // 18 groups x 8 k = 144
            if (g + 1 < 18) {
                const float* Wn = Wz + (size_t)(g + 1) * 8 * EE;
                #pragma unroll
                for (int j = 0; j < 8; ++j) {
                    n0[j] = Wn[(size_t)j * EE + c0];
                    n1[j] = Wn[(size_t)j * EE + c1];
                    n2[j] = has2 ? Wn[(size_t)j * EE + c2] : 0.f;
                }
            }
            const int kb0 = g * 8;
            #pragma unroll
            for (int j4 = 0; j4 < 2; ++j4) {
                #pragma unroll
                for (int r = 0; r < 8; ++r) {
                    float4 cv = *((const float4*)&C8[r * 148 + kb0 + j4 * 4]);
                    const int j = j4 * 4;
                    a0[r] += cv.x * w0[j] + cv.y * w0[j + 1] + cv.z * w0[j + 2] + cv.w * w0[j + 3];
                    a1[r] += cv.x * w1[j] + cv.y * w1[j + 1] + cv.z * w1[j + 2] + cv.w * w1[j + 3];
                    a2[r] += cv.x * w2[j] + cv.y * w2[j + 1] + cv.z * w2[j + 2] + cv.w * w2[j + 3];
                }
            }
            #pragma unroll
            for (int j = 0; j < 8; ++j) { w0[j] = n0[j]; w1[j] = n1[j]; w2[j] = n2[j]; }
        }
        float b0 = bz[c0], b1 = bz[c1], b2 = has2 ? bz[c2] : 0.f;
        #pragma unroll
        for (int r = 0; r < 8; ++r) {
            T8[r * 580 + c0] = a0[r] + b0;
            T8[r * 580 + c1] = a1[r] + b1;
            if (has2) T8[r * 580 + c2] = a2[r] + b2;
        }
    }
    __syncthreads();

    // ---- stage C: out8[:, col] = T8 @ Wi + bi for cols [cs*192, +192) ----
    if (tid < 192) {
        const int col = cs * 192 + tid;
        float acc[8] = {};
        float wv[16], wn[16];
        const float* Wp = Wi + col;
        #pragma unroll
        for (int j = 0; j < 16; ++j) wv[j] = Wp[(size_t)j * EE];
        for (int g = 0; g < 36; ++g) {          // 36 groups x 16 k = 576
            if (g + 1 < 36) {
                const float* Wn = Wp + (size_t)(g + 1) * 16 * EE;
                #pragma unroll
                for (int j = 0; j < 16; ++j) wn[j] = Wn[(size_t)j * EE];
            }
            const int kb0 = g * 16;
            #pragma unroll
            for (int j4 = 0; j4 < 4; ++j4) {
                #pragma unroll
                for (int r = 0; r < 8; ++r) {
                    float4 tv = *((const float4*)&T8[r * 580 + kb0 + j4 * 4]);
                    const int j = j4 * 4;
                    acc[r] += tv.x * wv[j] + tv.y * wv[j + 1] + tv.z * wv[j + 2] + tv.w * wv[j + 3];
                }
            }
            #pragma unroll
            for (int j = 0; j < 16; ++j) wv[j] = wn[j];
        }
        const float bic = bi[col];
        #pragma unroll
        for (int r = 0; r < 8; ++r)
            outp[(size_t)(row0 + r) * EE + col] = acc[r] + bic;
    }
}

// ---------------------------------------------------------------------------
// Fused scores + attention reduction (verbatim proven kernel).
// ---------------------------------------------------------------------------
__global__ __launch_bounds__(256) void k_attn(
    const int* __restrict__ state, const float* __restrict__ q,
    const float* __restrict__ kmat, const float* __restrict__ v,
    float* __restrict__ ctxsum, float* __restrict__ cnt)
{
    __shared__ int lst[NAG];
    __shared__ int cnt_s;
    __shared__ float w4[NH][NAG];
    __shared__ float qh[CMAX][HDIM + 1];
    __shared__ float kh[CMAX][HDIM + 1];
    __shared__ float Sl[CMAX][CMAX + 1];
    const int i = blockIdx.x, tid = threadIdx.x;
    if (tid == 0) cnt_s = 0;
    __syncthreads();
    {
        int xi = state[2 * i], yi = state[2 * i + 1];
        int xj = state[2 * tid], yj = state[2 * tid + 1];
        int dx = xi - xj; if (dx < 0) dx = -dx;
        int dy = yi - yj; if (dy < 0) dy = -dy;
        if (tid > i && dx <= 4 && dy <= 2) {
            int p = atomicAdd(&cnt_s, 1);
            lst[p] = tid;
        }
    }
    __syncthreads();
    const int c = cnt_s;                 // block-uniform
    if (tid == 0) cnt[i] = (float)c;
    if (c == 0) {
        for (int e = tid; e < EE; e += 256) ctxsum[i * EE + e] = 0.f;
        return;
    }
    if (c <= CMAX) {
        for (int h = 0; h < NH; ++h) {
            for (int idx = tid; idx < c * HDIM; idx += 256) {
                int jj = idx / HDIM, d = idx % HDIM;
                qh[jj][d] = q[lst[jj] * EE + h * HDIM + d];
                kh[jj][d] = kmat[lst[jj] * EE + h * HDIM + d];
            }
            __syncthreads();
            for (int pp = tid; pp < c * c; pp += 256) {
                int jj = pp / c, kk = pp % c;
                float acc = 0.f;
                for (int d = 0; d < HDIM; ++d) acc += qh[jj][d] * kh[kk][d];
                Sl[jj][kk] = acc * (1.0f / 12.0f);
            }
            __syncthreads();
            if (tid < c) {
                float m = -1e30f;
                for (int kk = 0; kk < c; ++kk) m = fmaxf(m, Sl[tid][kk]);
                float zz = 0.f;
                for (int kk = 0; kk < c; ++kk) zz += __expf(Sl[tid][kk] - m);
                float inv = 1.f / fmaxf(zz, 1e-9f);
                for (int kk = 0; kk < c; ++kk)
                    Sl[tid][kk] = __expf(Sl[tid][kk] - m) * inv;
            }
            __syncthreads();
            if (tid < c) {
                float s = 0.f;
                for (int jj = 0; jj < c; ++jj) s += Sl[jj][tid];
                w4[h][tid] = s;
            }
            __syncthreads();
        }
    } else {
        for (int idx = tid; idx < NH * c; idx += 256) w4[idx / c][idx % c] = 0.f;
        __syncthreads();
        for (int pnh = tid; pnh < NH * c; pnh += 256) {
            int h = pnh / c, jj = pnh % c;
            const float* qrow = q + lst[jj] * EE + h * HDIM;
            float m = -1e30f;
            for (int kk = 0; kk < c; ++kk) {
                const float* krow = kmat + lst[kk] * EE + h * HDIM;
                float a = 0.f;
                for (int d = 0; d < HDIM; ++d) a += qrow[d] * krow[d];
                m = fmaxf(m, a * (1.0f / 12.0f));
            }
            float zz = 0.f;
            for (int kk = 0; kk < c; ++kk) {
                const float* krow = kmat + lst[kk] * EE + h * HDIM;
                float a = 0.f;
                for (int d = 0; d < HDIM; ++d) a += qrow[d] * krow[d];
                zz += __expf(a * (1.0f / 12.0f) - m);
            }
            float inv = 1.f / fmaxf(zz, 1e-9f);
            for (int kk = 0; kk < c; ++kk) {
                const float* krow = kmat + lst[kk] * EE + h * HDIM;
                float a = 0.f;
                for (int d = 0; d < HDIM; ++d) a += qrow[d] * krow[d];
                atomicAdd(&w4[h][kk], __expf(a * (1.0f / 12.0f) - m) * inv);
            }
        }
        __syncthreads();
    }
    for (int e = tid; e < EE; e += 256) {
        int h = e / HDIM;
        float a0 = 0.f, a1 = 0.f;
        int t = 0;
        for (; t + 1 < c; t += 2) {
            a0 += w4[h][t] * v[lst[t] * EE + e];
            a1 += w4[h][t + 1] * v[lst[t + 1] * EE + e];
        }
        if (t < c) a0 += w4[h][t] * v[lst[t] * EE + e];
        ctxsum[i * EE + e] = a0 + a1;
    }
}

// ===========================================================================
// k_tail: per 2 agents, REFERENCE order (no precomputed Wc/bvec):
//   g2 = ctx2 @ Wo + cnt*bo      (2 x 576, LDS)
//   h2 = g2 @ W_O                (2 x 144, LDS)
//   dueling head (waves 0-1, one agent each)
// Grid 128 x 2 agents.
// ===========================================================================
__global__ __launch_bounds__(256) void k_tail(
    const float* __restrict__ ctx, const float* __restrict__ cnt,
    const float* __restrict__ Wo, const float* __restrict__ bo,
    const float* __restrict__ W_O,
    const float* __restrict__ W_val, const float* __restrict__ b_val,
    const float* __restrict__ W_adv, const float* __restrict__ b_adv,
    float* __restrict__ out)
{
    __shared__ float c2[2 * 580];
    __shared__ float g2[2 * 580];
    __shared__ float h2[2 * DD];
    const int b = blockIdx.x, tid = threadIdx.x;
    const int a0 = b * 2;
    for (int idx = tid; idx < 2 * (EE / 4); idx += 256) {
        int a = idx / (EE / 4), k4 = idx % (EE / 4);
        *((float4*)&c2[a * 580 + k4 * 4]) =
            *(const float4*)(ctx + (size_t)(a0 + a) * EE + k4 * 4);
    }
    __syncthreads();

    // ---- g2 = ctx2 @ Wo + cnt*bo (cols c0=tid, c1=tid+256, c2 if tid<64) ----
    {
        const int c0 = tid, c1 = tid + 256, cc2 = tid + 512;
        const bool has2 = (tid < 64);
        float a00 = 0.f, a01 = 0.f, a02 = 0.f;   // agent 0
        float a10 = 0.f, a11 = 0.f, a12 = 0.f;   // agent 1
        float w0[8], w1[8], w2[8], n0[8], n1[8], n2[8];
        #pragma unroll
        for (int j = 0; j < 8; ++j) {
            w0[j] = Wo[(size_t)j * EE + c0];
            w1[j] = Wo[(size_t)j * EE + c1];
            w2[j] = has2 ? Wo[(size_t)j * EE + cc2] : 0.f;
        }
        for (int g = 0; g < 72; ++g) {          // 72 groups x 8 k = 576
            if (g + 1 < 72) {
                const float* Wn = Wo + (size_t)(g + 1) * 8 * EE;
                #pragma unroll
                for (int j = 0; j < 8; ++j) {
                    n0[j] = Wn[(size_t)j * EE + c0];
                    n1[j] = Wn[(size_t)j * EE + c1];
                    n2[j] = has2 ? Wn[(size_t)j * EE + cc2] : 0.f;
                }
            }
            const int kb0 = g * 8;
            #pragma unroll
            for (int j4 = 0; j4 < 2; ++j4) {
                float4 x0 = *((const float4*)&c2[0 * 580 + kb0 + j4 * 4]);
                float4 x1 = *((const float4*)&c2[1 * 580 + kb0 + j4 * 4]);
                const int j = j4 * 4;
                a00 += x0.x * w0[j] + x0.y * w0[j + 1] + x0.z * w0[j + 2] + x0.w * w0[j + 3];
                a01 += x0.x * w1[j] + x0.y * w1[j + 1] + x0.z * w1[j + 2] + x0.w * w1[j + 3];
                a02 += x0.x * w2[j] + x0.y * w2[j + 1] + x0.z * w2[j + 2] + x0.w * w2[j + 3];
                a10 += x1.x * w0[j] + x1.y * w0[j + 1] + x1.z * w0[j + 2] + x1.w * w0[j + 3];
                a11 += x1.x * w1[j] + x1.y * w1[j + 1] + x1.z * w1[j + 2] + x1.w * w1[j + 3];
                a12 += x1.x * w2[j] + x1.y * w2[j + 1] + x1.z * w2[j + 2] + x1.w * w2[j + 3];
            }
            #pragma unroll
            for (int j = 0; j < 8; ++j) { w0[j] = n0[j]; w1[j] = n1[j]; w2[j] = n2[j]; }
        }
        const float ct0 = cnt[a0], ct1 = cnt[a0 + 1];
        g2[0 * 580 + c0] = a00 + ct0 * bo[c0];
        g2[1 * 580 + c0] = a10 + ct1 * bo[c0];
        g2[0 * 580 + c1] = a01 + ct0 * bo[c1];
        g2[1 * 580 + c1] = a11 + ct1 * bo[c1];
        if (has2) {
            g2[0 * 580 + cc2] = a02 + ct0 * bo[cc2];
            g2[1 * 580 + cc2] = a12 + ct1 * bo[cc2];
        }
    }
    __syncthreads();

    // ---- h2 = g2 @ W_O (144 cols, threads 0..143) ----
    if (tid < DD) {
        const int col = tid;
        float ac0 = 0.f, ac1 = 0.f;
        float wv[8], wn[8];
        const float* Wp = W_O + col;
        #pragma unroll
        for (int j = 0; j < 8; ++j) wv[j] = Wp[(size_t)j * DD];
        for (int g = 0; g < 72; ++g) {
            if (g + 1 < 72) {
                const float* Wn = Wp + (size_t)(g + 1) * 8 * DD;
                #pragma unroll
                for (int j = 0; j < 8; ++j) wn[j] = Wn[(size_t)j * DD];
            }
            const int kb0 = g * 8;
            #pragma unroll
            for (int j4 = 0; j4 < 2; ++j4) {
                float4 x0 = *((const float4*)&g2[0 * 580 + kb0 + j4 * 4]);
                float4 x1 = *((const float4*)&g2[1 * 580 + kb0 + j4 * 4]);
                const int j = j4 * 4;
                ac0 += x0.x * wv[j] + x0.y * wv[j + 1] + x0.z * wv[j + 2] + x0.w * wv[j + 3];
                ac1 += x1.x * wv[j] + x1.y * wv[j + 1] + x1.z * wv[j + 2] + x1.w * wv[j + 3];
            }
            #pragma unroll
            for (int j = 0; j < 8; ++j) wv[j] = wn[j];
        }
        h2[0 * DD + col] = ac0;
        h2[1 * DD + col] = ac1;
    }
    __syncthreads();

    // ---- dueling head: wave 0 -> agent 0, wave 1 -> agent 1 ----
    const int wave = tid >> 6, lane = tid & 63;
    if (wave < 2) {
        const int ag = wave;
        float h0 = h2[ag * DD + lane], h1 = h2[ag * DD + lane + 64];
        float hh2 = (lane < 16) ? h2[ag * DD + lane + 128] : 0.f;
        float red[6];
        for (int o = 0; o < 6; ++o) {
            float p;
            if (o < 5) {
                p = h0 * W_adv[lane * ACT + o] + h1 * W_adv[(lane + 64) * ACT + o];
                if (lane < 16) p += hh2 * W_adv[(lane + 128) * ACT + o];
            } else {
                p = h0 * W_val[lane] + h1 * W_val[lane + 64];
                if (lane < 16) p += hh2 * W_val[lane + 128];
            }
            for (int off = 32; off; off >>= 1) p += __shfl_xor(p, off);
            red[o] = p;
        }
        if (lane == 0) {
            float a[ACT], mean = 0.f;
            for (int o = 0; o < ACT; ++o) { a[o] = red[o] + b_adv[o]; mean += a[o]; }
            mean *= (1.0f / ACT);
            float V = red[5] + b_val[0];
            for (int o = 0; o < ACT; ++o) out[(a0 + ag) * ACT + o] = V + a[o] - mean;
        }
    }
}

// ---------------------------------------------------------------------------
extern "C" void kernel_launch(void* const* d_in, const int* in_sizes, int n_in,
                              void* d_out, int out_size, void* d_ws, size_t ws_size,
                              hipStream_t stream)
{
    const float* hidden = (const float*)d_in[0];
    const float* action = (const float*)d_in[1];
    const int*   state  = (const int*)d_in[2];

    float* ws = (float*)d_ws;
    float* q    = ws;                        // 256*576 each
    float* kb   = q   + NAG * EE;
    float* v    = kb  + NAG * EE;
    float* ctx  = v   + NAG * EE;
    float* cnt  = ctx + NAG * EE;            // 256
    // total ws ~2.4 MB

    // k_qkv: fused enc + two-stage QKV (reference order), 288 blocks
    k_qkv<<<288, 256, 0, stream>>>(hidden, action,
        (const float*)d_in[3], (const float*)d_in[4],
        (const float*)d_in[5], (const float*)d_in[6],
        (const float*)d_in[11], (const float*)d_in[12],
        (const float*)d_in[7], (const float*)d_in[8],
        (const float*)d_in[13], (const float*)d_in[14],
        (const float*)d_in[9], (const float*)d_in[10],
        (const float*)d_in[15], (const float*)d_in[16],
        q, kb, v);

    // fused scores+attention (unchanged)
    k_attn<<<NAG, 256, 0, stream>>>(state, q, kb, v, ctx, cnt);

    // k_tail: two-stage tail (reference order) + dueling head, 128 blocks
    k_tail<<<128, 256, 0, stream>>>(ctx, cnt,
        (const float*)d_in[17], (const float*)d_in[18], (const float*)d_in[19],
        (const float*)d_in[20], (const float*)d_in[21],
        (const float*)d_in[22], (const float*)d_in[23], (float*)d_out);
}